// Round 1
// baseline (3909.780 us; speedup 1.0000x reference)
//
#include <hip/hip_runtime.h>
#include <hip/hip_cooperative_groups.h>

namespace cg = cooperative_groups;

// ---- problem constants (match reference) ----
#define NYI 200
#define NXI 200
#define PMLW 20
#define FDP 2
#define PADW (PMLW + FDP)          // 22
#define NYP (NYI + 2 * PADW)       // 244
#define NXP (NXI + 2 * PADW)       // 244
#define NP  (NYP * NXP)            // 59536
#define NSH 2
#define NRECV 100
#define NTT 120
#define TOTC (NSH * NP)            // 119072

#define DTC   0.0005f
#define RH    0.25f                // 1/DY = 1/DX
#define RH2   0.0625f              // 1/DY^2
#define C1A   (1.0f / 12.0f)
#define C1B   (2.0f / 3.0f)
#define C2A   (1.0f / 12.0f)
#define C2B   (4.0f / 3.0f)

#define CELL_BLOCKS ((TOTC + 255) / 256)   // fallback grid

// persistent cooperative config: 117 blocks x 512 thr x 2 cells = 119808 >= TOTC
#define NBLK_COOP 117
#define NTHR_COOP 512
#define HALF_CELLS (NBLK_COOP * NTHR_COOP)   // 59904

// ---- workspace layout (float offsets) ----
#define OFF_MAXV 0
#define OFF_AY   64
#define OFF_BY   (OFF_AY + NYP)
#define OFF_AX   (OFF_BY + NYP)
#define OFF_BX   (OFF_AX + NXP)
#define OFF_V2   (OFF_BX + NXP)
#define OFF_SPV  (OFF_V2 + NP)
#define OFF_F    (OFF_SPV + NP)      // 12 * TOTC floats of fields

__device__ __forceinline__ float cellv(const float* p, int base, int y, int x) {
    if ((unsigned)y >= (unsigned)NYP || (unsigned)x >= (unsigned)NXP) return 0.0f;
    return p[base + y * NXP + x];
}

__global__ void reduce_max_kernel(const float* __restrict__ v, float* __restrict__ out) {
    __shared__ float sm[256];
    float m = 0.0f;
    for (int i = threadIdx.x; i < NYI * NXI; i += 256)
        m = fmaxf(m, v[i]);
    sm[threadIdx.x] = m;
    __syncthreads();
    for (int s = 128; s > 0; s >>= 1) {
        if (threadIdx.x < s) sm[threadIdx.x] = fmaxf(sm[threadIdx.x], sm[threadIdx.x + s]);
        __syncthreads();
    }
    if (threadIdx.x == 0) out[0] = sm[0];
}

__global__ void setup_kernel(const float* __restrict__ v,
                             const float* __restrict__ scat,
                             const float* __restrict__ maxv,
                             float* __restrict__ ay, float* __restrict__ by,
                             float* __restrict__ ax, float* __restrict__ bx,
                             float* __restrict__ v2dt2, float* __restrict__ spv) {
    int gtid = blockIdx.x * blockDim.x + threadIdx.x;
    int nth  = gridDim.x * blockDim.x;

    for (int idx = gtid; idx < NP; idx += nth) {
        int y = idx / NXP;
        int x = idx - y * NXP;
        int yi = min(max(y - PADW, 0), NYI - 1);
        int xi = min(max(x - PADW, 0), NXI - 1);
        float vp = v[yi * NXI + xi];
        v2dt2[idx] = vp * vp * DTC * DTC;
        float sp = 0.0f;
        int ys = y - PADW, xs = x - PADW;
        if (ys >= 0 && ys < NYI && xs >= 0 && xs < NXI)
            sp = scat[ys * NXI + xs];
        spv[idx] = 2.0f * vp * DTC * DTC * sp;
    }

    if (gtid < NYP + NXP) {
        float mv = maxv[0];
        int isY = gtid < NYP;
        int j   = isY ? gtid : gtid - NYP;
        int n   = isY ? NYP : NXP;
        float h = 4.0f;
        float xf = (float)j;
        float lo = (float)(FDP + PMLW);
        float hi = (float)(n - 1 - FDP - PMLW);
        float d1 = fminf(fmaxf((lo - xf) / (float)PMLW, 0.0f), 1.0f);
        float d2 = fminf(fmaxf((xf - hi) / (float)PMLW, 0.0f), 1.0f);
        float d  = fmaxf(d1, d2);
        float sigma = 3.0f * mv * 6.9077552790f / (2.0f * (float)PMLW * h) * d * d;
        float alpha = 6.2831853072f * 25.0f * (1.0f - d);
        float a  = expf(-(sigma + alpha) * DTC);
        float bb = sigma / (sigma + alpha + 1e-9f) * (a - 1.0f);
        if (isY) { ay[j] = a; by[j] = bb; }
        else     { ax[j] = a; bx[j] = bb; }
    }
}

// ---- persistent cooperative kernel: all NTT steps in one launch ----
// Pointwise state (zeta, own-psi, field at t-1) lives in registers for the
// whole run; only neighbor-read fields (wfc/wfcsc, psi*) go through memory.
__global__ __launch_bounds__(NTHR_COOP)
void timeloop_kernel(float* __restrict__ F,
                     const float* __restrict__ v2dt2, const float* __restrict__ spvg,
                     const float* __restrict__ ayg, const float* __restrict__ byg,
                     const float* __restrict__ axg, const float* __restrict__ bxg,
                     const float* __restrict__ amps,
                     const int* __restrict__ sloc, const int* __restrict__ rloc,
                     float* __restrict__ out)
{
    cg::grid_group grid = cg::this_grid();

    float* wfc    = F + 0 * TOTC;
    float* wfp    = F + 1 * TOTC;
    float* psiy   = F + 2 * TOTC;
    float* psix   = F + 3 * TOTC;
    float* wfcsc  = F + 6 * TOTC;
    float* wfpsc  = F + 7 * TOTC;
    float* psiysc = F + 8 * TOTC;
    float* psixsc = F + 9 * TOTC;

    // XCD-contiguous bijective block remap (m204): contiguous row bands per
    // XCD -> halo reads stay in the local L2 slice for all NTT steps.
    const int q = NBLK_COOP / 8, r = NBLK_COOP % 8;
    const int xcd = (int)blockIdx.x % 8, bi = (int)blockIdx.x / 8;
    const int swz = (xcd < r) ? (xcd * (q + 1) + bi)
                              : (r * (q + 1) + (xcd - r) * q + bi);
    const int gid = swz * NTHR_COOP + (int)threadIdx.x;

    int   fid[2], yy[2], xx[2], bs[2], aoff[2];
    float ayc[2], byc[2], axc[2], bxc[2], v2c[2], spc[2];
    bool  act[2], srcf[2];

#pragma unroll
    for (int c = 0; c < 2; ++c) {
        int f = gid + c * HALF_CELLS;
        act[c] = f < TOTC;
        int fc = act[c] ? f : 0;
        int b  = (fc >= NP) ? 1 : 0;
        int cell = fc - b * NP;
        int y = cell / NXP;
        int x = cell - y * NXP;
        fid[c] = fc; yy[c] = y; xx[c] = x; bs[c] = b * NP;
        ayc[c] = ayg[y]; byc[c] = byg[y]; axc[c] = axg[x]; bxc[c] = bxg[x];
        v2c[c] = v2dt2[cell]; spc[c] = spvg[cell];
        int sy = sloc[b * 2 + 0] + PADW, sx = sloc[b * 2 + 1] + PADW;
        srcf[c] = act[c] && (y == sy) && (x == sx);
        aoff[c] = b * NTT;
    }

    const bool isRec = gid < NSH * NRECV;
    int rbase = 0;
    if (isRec) {
        int rb = gid / NRECV;
        int ry = rloc[gid * 2 + 0] + PADW;
        int rx = rloc[gid * 2 + 1] + PADW;
        rbase = rb * NP + ry * NXP + rx;
    }

    // register-resident pointwise state (reference starts all-zero)
    float psiyR[2]   = {0.f, 0.f}, psixR[2]   = {0.f, 0.f};
    float psiyscR[2] = {0.f, 0.f}, psixscR[2] = {0.f, 0.f};
    float zetyR[2]   = {0.f, 0.f}, zetxR[2]   = {0.f, 0.f};
    float zetyscR[2] = {0.f, 0.f}, zetxscR[2] = {0.f, 0.f};
    float wprevB[2]  = {0.f, 0.f}, wprevS[2]  = {0.f, 0.f};

    for (int t = 0; t < NTT; ++t) {
        // ---- phase A: psi update (d1 of wavefields) ----
#pragma unroll
        for (int c = 0; c < 2; ++c) {
            if (!act[c]) continue;
            const int base = bs[c], y = yy[c], x = xx[c], id = fid[c];
            float d1yw = RH * (C1A * (cellv(wfc, base, y - 2, x) - cellv(wfc, base, y + 2, x)) +
                               C1B * (cellv(wfc, base, y + 1, x) - cellv(wfc, base, y - 1, x)));
            float d1xw = RH * (C1A * (cellv(wfc, base, y, x - 2) - cellv(wfc, base, y, x + 2)) +
                               C1B * (cellv(wfc, base, y, x + 1) - cellv(wfc, base, y, x - 1)));
            psiyR[c] = ayc[c] * psiyR[c] + byc[c] * d1yw;
            psixR[c] = axc[c] * psixR[c] + bxc[c] * d1xw;
            psiy[id] = psiyR[c];
            psix[id] = psixR[c];

            float d1ys = RH * (C1A * (cellv(wfcsc, base, y - 2, x) - cellv(wfcsc, base, y + 2, x)) +
                               C1B * (cellv(wfcsc, base, y + 1, x) - cellv(wfcsc, base, y - 1, x)));
            float d1xs = RH * (C1A * (cellv(wfcsc, base, y, x - 2) - cellv(wfcsc, base, y, x + 2)) +
                               C1B * (cellv(wfcsc, base, y, x + 1) - cellv(wfcsc, base, y, x - 1)));
            psiyscR[c] = ayc[c] * psiyscR[c] + byc[c] * d1ys;
            psixscR[c] = axc[c] * psixscR[c] + bxc[c] * d1xs;
            psiysc[id] = psiyscR[c];
            psixsc[id] = psixscR[c];
        }
        grid.sync();

        // ---- phase B: zeta + time update ----
#pragma unroll
        for (int c = 0; c < 2; ++c) {
            if (!act[c]) continue;
            const int base = bs[c], y = yy[c], x = xx[c], id = fid[c];

            float w0 = wfc[id];
            float d2yw = RH2 * (C2B * (cellv(wfc, base, y - 1, x) + cellv(wfc, base, y + 1, x)) -
                                C2A * (cellv(wfc, base, y - 2, x) + cellv(wfc, base, y + 2, x)) -
                                2.5f * w0);
            float d2xw = RH2 * (C2B * (cellv(wfc, base, y, x - 1) + cellv(wfc, base, y, x + 1)) -
                                C2A * (cellv(wfc, base, y, x - 2) + cellv(wfc, base, y, x + 2)) -
                                2.5f * w0);
            float d1yp = RH * (C1A * (cellv(psiy, base, y - 2, x) - cellv(psiy, base, y + 2, x)) +
                               C1B * (cellv(psiy, base, y + 1, x) - cellv(psiy, base, y - 1, x)));
            float d1xp = RH * (C1A * (cellv(psix, base, y, x - 2) - cellv(psix, base, y, x + 2)) +
                               C1B * (cellv(psix, base, y, x + 1) - cellv(psix, base, y, x - 1)));
            float ty = d2yw + d1yp;
            float tx = d2xw + d1xp;
            zetyR[c] = ayc[c] * zetyR[c] + byc[c] * ty;
            zetxR[c] = axc[c] * zetxR[c] + bxc[c] * tx;
            float lap = ty + zetyR[c] + tx + zetxR[c];

            float ws0 = wfcsc[id];
            float d2ys = RH2 * (C2B * (cellv(wfcsc, base, y - 1, x) + cellv(wfcsc, base, y + 1, x)) -
                                C2A * (cellv(wfcsc, base, y - 2, x) + cellv(wfcsc, base, y + 2, x)) -
                                2.5f * ws0);
            float d2xs = RH2 * (C2B * (cellv(wfcsc, base, y, x - 1) + cellv(wfcsc, base, y, x + 1)) -
                                C2A * (cellv(wfcsc, base, y, x - 2) + cellv(wfcsc, base, y, x + 2)) -
                                2.5f * ws0);
            float d1yps = RH * (C1A * (cellv(psiysc, base, y - 2, x) - cellv(psiysc, base, y + 2, x)) +
                                C1B * (cellv(psiysc, base, y + 1, x) - cellv(psiysc, base, y - 1, x)));
            float d1xps = RH * (C1A * (cellv(psixsc, base, y, x - 2) - cellv(psixsc, base, y, x + 2)) +
                                C1B * (cellv(psixsc, base, y, x + 1) - cellv(psixsc, base, y, x - 1)));
            float tys = d2ys + d1yps;
            float txs = d2xs + d1xps;
            zetyscR[c] = ayc[c] * zetyscR[c] + byc[c] * tys;
            zetxscR[c] = axc[c] * zetxscR[c] + bxc[c] * txs;
            float lapsc = tys + zetyscR[c] + txs + zetxscR[c];

            float wn   = v2c[c] * lap   + 2.0f * w0  - wprevB[c];
            float wnsc = v2c[c] * lapsc + 2.0f * ws0 - wprevS[c] + spc[c] * lap;
            if (srcf[c]) wn += v2c[c] * amps[aoff[c] + t];

            wfp[id]   = wn;
            wfpsc[id] = wnsc;
            wprevB[c] = w0;
            wprevS[c] = ws0;
        }
        grid.sync();

        // swap (uniform local pointer swap) and record receivers for step t
        { float* tmp = wfc; wfc = wfp; wfp = tmp;
          tmp = wfcsc; wfcsc = wfpsc; wfpsc = tmp; }
        if (isRec) out[gid * NTT + t] = wfcsc[rbase];
    }
}

// ---- fallback path (identical to previous working version) ----
__global__ void phaseA_kernel(int t,
    const float* __restrict__ wfc, const float* __restrict__ wfcsc,
    float* __restrict__ psiy, float* __restrict__ psix,
    float* __restrict__ psiysc, float* __restrict__ psixsc,
    const float* __restrict__ ay, const float* __restrict__ by,
    const float* __restrict__ ax, const float* __restrict__ bx,
    const int* __restrict__ rloc, float* __restrict__ out)
{
    int idx = blockIdx.x * blockDim.x + threadIdx.x;

    if (idx < NSH * NRECV && t > 0) {
        int b = idx / NRECV;
        int ry = rloc[idx * 2 + 0] + PADW;
        int rx = rloc[idx * 2 + 1] + PADW;
        out[idx * NTT + (t - 1)] = wfcsc[b * NP + ry * NXP + rx];
    }

    if (idx >= TOTC) return;
    int b = (idx >= NP) ? 1 : 0;
    int cell = idx - b * NP;
    int y = cell / NXP;
    int x = cell - y * NXP;
    int base = b * NP;
    float ayv = ay[y], byv = by[y], axv = ax[x], bxv = bx[x];

    float d1yw = RH * (C1A * (cellv(wfc, base, y - 2, x) - cellv(wfc, base, y + 2, x)) +
                       C1B * (cellv(wfc, base, y + 1, x) - cellv(wfc, base, y - 1, x)));
    float d1xw = RH * (C1A * (cellv(wfc, base, y, x - 2) - cellv(wfc, base, y, x + 2)) +
                       C1B * (cellv(wfc, base, y, x + 1) - cellv(wfc, base, y, x - 1)));
    psiy[idx] = ayv * psiy[idx] + byv * d1yw;
    psix[idx] = axv * psix[idx] + bxv * d1xw;

    float d1ys = RH * (C1A * (cellv(wfcsc, base, y - 2, x) - cellv(wfcsc, base, y + 2, x)) +
                       C1B * (cellv(wfcsc, base, y + 1, x) - cellv(wfcsc, base, y - 1, x)));
    float d1xs = RH * (C1A * (cellv(wfcsc, base, y, x - 2) - cellv(wfcsc, base, y, x + 2)) +
                       C1B * (cellv(wfcsc, base, y, x + 1) - cellv(wfcsc, base, y, x - 1)));
    psiysc[idx] = ayv * psiysc[idx] + byv * d1ys;
    psixsc[idx] = axv * psixsc[idx] + bxv * d1xs;
}

__global__ void phaseB_kernel(int t,
    const float* __restrict__ wfc, float* __restrict__ wfp,
    const float* __restrict__ wfcsc, float* __restrict__ wfpsc,
    const float* __restrict__ psiy, const float* __restrict__ psix,
    float* __restrict__ zety, float* __restrict__ zetx,
    const float* __restrict__ psiysc, const float* __restrict__ psixsc,
    float* __restrict__ zetysc, float* __restrict__ zetxsc,
    const float* __restrict__ v2dt2, const float* __restrict__ spv,
    const float* __restrict__ ay, const float* __restrict__ by,
    const float* __restrict__ ax, const float* __restrict__ bx,
    const float* __restrict__ amps, const int* __restrict__ sloc)
{
    int idx = blockIdx.x * blockDim.x + threadIdx.x;
    if (idx >= TOTC) return;
    int b = (idx >= NP) ? 1 : 0;
    int cell = idx - b * NP;
    int y = cell / NXP;
    int x = cell - y * NXP;
    int base = b * NP;
    float ayv = ay[y], byv = by[y], axv = ax[x], bxv = bx[x];

    float w0 = wfc[idx];
    float d2yw = RH2 * (C2B * (cellv(wfc, base, y - 1, x) + cellv(wfc, base, y + 1, x)) -
                        C2A * (cellv(wfc, base, y - 2, x) + cellv(wfc, base, y + 2, x)) -
                        2.5f * w0);
    float d2xw = RH2 * (C2B * (cellv(wfc, base, y, x - 1) + cellv(wfc, base, y, x + 1)) -
                        C2A * (cellv(wfc, base, y, x - 2) + cellv(wfc, base, y, x + 2)) -
                        2.5f * w0);
    float d1yp = RH * (C1A * (cellv(psiy, base, y - 2, x) - cellv(psiy, base, y + 2, x)) +
                       C1B * (cellv(psiy, base, y + 1, x) - cellv(psiy, base, y - 1, x)));
    float d1xp = RH * (C1A * (cellv(psix, base, y, x - 2) - cellv(psix, base, y, x + 2)) +
                       C1B * (cellv(psix, base, y, x + 1) - cellv(psix, base, y, x - 1)));
    float ty = d2yw + d1yp;
    float tx = d2xw + d1xp;
    float zy = ayv * zety[idx] + byv * ty;
    float zx = axv * zetx[idx] + bxv * tx;
    zety[idx] = zy;
    zetx[idx] = zx;
    float lap = ty + zy + tx + zx;

    float ws0 = wfcsc[idx];
    float d2ys = RH2 * (C2B * (cellv(wfcsc, base, y - 1, x) + cellv(wfcsc, base, y + 1, x)) -
                        C2A * (cellv(wfcsc, base, y - 2, x) + cellv(wfcsc, base, y + 2, x)) -
                        2.5f * ws0);
    float d2xs = RH2 * (C2B * (cellv(wfcsc, base, y, x - 1) + cellv(wfcsc, base, y, x + 1)) -
                        C2A * (cellv(wfcsc, base, y, x - 2) + cellv(wfcsc, base, y, x + 2)) -
                        2.5f * ws0);
    float d1yps = RH * (C1A * (cellv(psiysc, base, y - 2, x) - cellv(psiysc, base, y + 2, x)) +
                        C1B * (cellv(psiysc, base, y + 1, x) - cellv(psiysc, base, y - 1, x)));
    float d1xps = RH * (C1A * (cellv(psixsc, base, y, x - 2) - cellv(psixsc, base, y, x + 2)) +
                        C1B * (cellv(psixsc, base, y, x + 1) - cellv(psixsc, base, y, x - 1)));
    float tys = d2ys + d1yps;
    float txs = d2xs + d1xps;
    float zys = ayv * zetysc[idx] + byv * tys;
    float zxs = axv * zetxsc[idx] + bxv * txs;
    zetysc[idx] = zys;
    zetxsc[idx] = zxs;
    float lapsc = tys + zys + txs + zxs;

    float v2 = v2dt2[cell];
    float wn   = v2 * lap   + 2.0f * w0  - wfp[idx];
    float wnsc = v2 * lapsc + 2.0f * ws0 - wfpsc[idx] + spv[cell] * lap;

    int sy0 = sloc[0] + PADW, sx0 = sloc[1] + PADW;
    int sy1 = sloc[2] + PADW, sx1 = sloc[3] + PADW;
    if (b == 0 && y == sy0 && x == sx0) wn += v2 * amps[t];
    if (b == 1 && y == sy1 && x == sx1) wn += v2 * amps[NTT + t];

    wfp[idx]   = wn;
    wfpsc[idx] = wnsc;
}

__global__ void record_kernel(const float* __restrict__ wfcsc,
                              const int* __restrict__ rloc,
                              float* __restrict__ out) {
    int idx = threadIdx.x;
    if (idx < NSH * NRECV) {
        int b = idx / NRECV;
        int ry = rloc[idx * 2 + 0] + PADW;
        int rx = rloc[idx * 2 + 1] + PADW;
        out[idx * NTT + (NTT - 1)] = wfcsc[b * NP + ry * NXP + rx];
    }
}

extern "C" void kernel_launch(void* const* d_in, const int* in_sizes, int n_in,
                              void* d_out, int out_size, void* d_ws, size_t ws_size,
                              hipStream_t stream) {
    const float* v    = (const float*)d_in[0];
    const float* scat = (const float*)d_in[1];
    const float* amps = (const float*)d_in[2];
    const int* sloc = (const int*)d_in[3];
    const int* rloc = (const int*)d_in[4];
    float* ws = (float*)d_ws;
    float* out = (float*)d_out;

    float* ay  = ws + OFF_AY;
    float* by  = ws + OFF_BY;
    float* ax  = ws + OFF_AX;
    float* bx  = ws + OFF_BX;
    float* v2  = ws + OFF_V2;
    float* spv = ws + OFF_SPV;
    float* F   = ws + OFF_F;

    // zero the 12 field arrays (ws is poisoned 0xAA before every timed call)
    hipMemsetAsync(F, 0, sizeof(float) * 12 * TOTC, stream);

    reduce_max_kernel<<<1, 256, 0, stream>>>(v, ws + OFF_MAXV);
    setup_kernel<<<(NP + 255) / 256, 256, 0, stream>>>(
        v, scat, ws + OFF_MAXV, ay, by, ax, bx, v2, spv);

    // single persistent cooperative launch for all NTT timesteps
    float* Fp = F;
    const float* v2p = v2; const float* spvp = spv;
    const float* ayp = ay; const float* byp = by;
    const float* axp = ax; const float* bxp = bx;
    const float* ampsp = amps; const int* slocp = sloc; const int* rlocp = rloc;
    float* outp = out;
    void* kargs[] = { &Fp, &v2p, &spvp, &ayp, &byp, &axp, &bxp,
                      &ampsp, &slocp, &rlocp, &outp };
    hipError_t err = hipLaunchCooperativeKernel(
        (const void*)timeloop_kernel, dim3(NBLK_COOP), dim3(NTHR_COOP),
        kargs, 0, stream);

    if (err != hipSuccess) {
        // fallback: per-step launches (previous verified path)
        float* wfc    = F + 0 * TOTC;
        float* wfp    = F + 1 * TOTC;
        float* psiy   = F + 2 * TOTC;
        float* psix   = F + 3 * TOTC;
        float* zety   = F + 4 * TOTC;
        float* zetx   = F + 5 * TOTC;
        float* wfcsc  = F + 6 * TOTC;
        float* wfpsc  = F + 7 * TOTC;
        float* psiysc = F + 8 * TOTC;
        float* psixsc = F + 9 * TOTC;
        float* zetysc = F + 10 * TOTC;
        float* zetxsc = F + 11 * TOTC;
        for (int t = 0; t < NTT; ++t) {
            phaseA_kernel<<<CELL_BLOCKS, 256, 0, stream>>>(
                t, wfc, wfcsc, psiy, psix, psiysc, psixsc,
                ay, by, ax, bx, rloc, out);
            phaseB_kernel<<<CELL_BLOCKS, 256, 0, stream>>>(
                t, wfc, wfp, wfcsc, wfpsc,
                psiy, psix, zety, zetx,
                psiysc, psixsc, zetysc, zetxsc,
                v2, spv, ay, by, ax, bx, amps, sloc);
            float* tmp;
            tmp = wfc;   wfc = wfp;     wfp = tmp;
            tmp = wfcsc; wfcsc = wfpsc; wfpsc = tmp;
        }
        record_kernel<<<1, 256, 0, stream>>>(wfcsc, rloc, out);
    }
}

// Round 2
// 1438.834 us; speedup vs baseline: 2.7173x; 2.7173x over previous
//
#include <hip/hip_runtime.h>

// ---- problem constants (match reference) ----
#define NYI 200
#define NXI 200
#define PMLW 20
#define FDP 2
#define PADW (PMLW + FDP)          // 22
#define NYP (NYI + 2 * PADW)       // 244
#define NXP (NXI + 2 * PADW)       // 244
#define NP  (NYP * NXP)            // 59536
#define NSH 2
#define NRECV 100
#define NTT 120
#define TOTC (NSH * NP)            // 119072

#define DTC   0.0005f
#define RH    0.25f                // 1/DY = 1/DX
#define RH2   0.0625f              // 1/DY^2
#define C1A   (1.0f / 12.0f)
#define C1B   (2.0f / 3.0f)
#define C2A   (1.0f / 12.0f)
#define C2B   (4.0f / 3.0f)

#define CELL_BLOCKS ((TOTC + 255) / 256)   // 466

// ---- workspace layout (float offsets) ----
#define OFF_MAXV 0
#define OFF_AY   64
#define OFF_BY   (OFF_AY + NYP)
#define OFF_AX   (OFF_BY + NYP)
#define OFF_BX   (OFF_AX + NXP)
#define OFF_V2   (OFF_BX + NXP)
#define OFF_SPV  (OFF_V2 + NP)
#define OFF_F    (OFF_SPV + NP)      // 16 * TOTC floats of fields

__global__ void reduce_max_kernel(const float* __restrict__ v, float* __restrict__ out) {
    __shared__ float sm[256];
    float m = 0.0f;
    for (int i = threadIdx.x; i < NYI * NXI; i += 256)
        m = fmaxf(m, v[i]);
    sm[threadIdx.x] = m;
    __syncthreads();
    for (int s = 128; s > 0; s >>= 1) {
        if (threadIdx.x < s) sm[threadIdx.x] = fmaxf(sm[threadIdx.x], sm[threadIdx.x + s]);
        __syncthreads();
    }
    if (threadIdx.x == 0) out[0] = sm[0];
}

__global__ void setup_kernel(const float* __restrict__ v,
                             const float* __restrict__ scat,
                             const float* __restrict__ maxv,
                             float* __restrict__ ay, float* __restrict__ by,
                             float* __restrict__ ax, float* __restrict__ bx,
                             float* __restrict__ v2dt2, float* __restrict__ spv) {
    int gtid = blockIdx.x * blockDim.x + threadIdx.x;
    int nth  = gridDim.x * blockDim.x;

    for (int idx = gtid; idx < NP; idx += nth) {
        int y = idx / NXP;
        int x = idx - y * NXP;
        int yi = min(max(y - PADW, 0), NYI - 1);
        int xi = min(max(x - PADW, 0), NXI - 1);
        float vp = v[yi * NXI + xi];
        v2dt2[idx] = vp * vp * DTC * DTC;
        float sp = 0.0f;
        int ys = y - PADW, xs = x - PADW;
        if (ys >= 0 && ys < NYI && xs >= 0 && xs < NXI)
            sp = scat[ys * NXI + xs];
        spv[idx] = 2.0f * vp * DTC * DTC * sp;
    }

    if (gtid < NYP + NXP) {
        float mv = maxv[0];
        int isY = gtid < NYP;
        int j   = isY ? gtid : gtid - NYP;
        int n   = isY ? NYP : NXP;
        float h = 4.0f;
        float xf = (float)j;
        float lo = (float)(FDP + PMLW);
        float hi = (float)(n - 1 - FDP - PMLW);
        float d1 = fminf(fmaxf((lo - xf) / (float)PMLW, 0.0f), 1.0f);
        float d2 = fminf(fmaxf((xf - hi) / (float)PMLW, 0.0f), 1.0f);
        float d  = fmaxf(d1, d2);
        float sigma = 3.0f * mv * 6.9077552790f / (2.0f * (float)PMLW * h) * d * d;
        float alpha = 6.2831853072f * 25.0f * (1.0f - d);
        float a  = expf(-(sigma + alpha) * DTC);
        float bb = sigma / (sigma + alpha + 1e-9f) * (a - 1.0f);
        if (isY) { ay[j] = a; by[j] = bb; }
        else     { ax[j] = a; bx[j] = bb; }
    }
}

// Fused per-step CPML update for one field (background or scattered).
// Recomputes neighbors' psi_new from psi_old + d1(w) (phase-A fusion), so a
// single launch per timestep suffices. psi is double-buffered (read Old /
// write New); zeta is pointwise in-place. Returns lap.
__device__ __forceinline__ float fused_lap(
    const float* __restrict__ w,
    const float* __restrict__ psiyO, const float* __restrict__ psixO,
    float* __restrict__ psiyN, float* __restrict__ psixN,
    float* __restrict__ zety, float* __restrict__ zetx,
    int base, int id, int y, int x,
    const float* __restrict__ ayg, const float* __restrict__ byg,
    const float* __restrict__ axg, const float* __restrict__ bxg)
{
    // register-stage w column [y-4..y+4, x] and row [y, x-4..x+4] (0 outside)
    float cw[9], rw[9];
#pragma unroll
    for (int k = 0; k < 9; ++k) {
        int yy = y - 4 + k;
        cw[k] = ((unsigned)yy < (unsigned)NYP) ? w[base + yy * NXP + x] : 0.0f;
        int xx = x - 4 + k;
        rw[k] = ((unsigned)xx < (unsigned)NXP) ? w[base + y * NXP + xx] : 0.0f;
    }
    // psi_new at the 5 positions needed for d1(psi_new) at (y,x) (and own store)
    float py[5], px[5];
#pragma unroll
    for (int j = 0; j < 5; ++j) {
        int yy = y - 2 + j;
        float vy = 0.0f;
        if ((unsigned)yy < (unsigned)NYP) {
            float d1 = RH * (C1A * (cw[j] - cw[j + 4]) + C1B * (cw[j + 3] - cw[j + 1]));
            vy = ayg[yy] * psiyO[base + yy * NXP + x] + byg[yy] * d1;
        }
        py[j] = vy;
        int xx = x - 2 + j;
        float vx = 0.0f;
        if ((unsigned)xx < (unsigned)NXP) {
            float d1 = RH * (C1A * (rw[j] - rw[j + 4]) + C1B * (rw[j + 3] - rw[j + 1]));
            vx = axg[xx] * psixO[base + y * NXP + xx] + bxg[xx] * d1;
        }
        px[j] = vx;
    }
    psiyN[id] = py[2];
    psixN[id] = px[2];

    float w0 = cw[4];
    float d2yw = RH2 * (C2B * (cw[3] + cw[5]) - C2A * (cw[2] + cw[6]) - 2.5f * w0);
    float d2xw = RH2 * (C2B * (rw[3] + rw[5]) - C2A * (rw[2] + rw[6]) - 2.5f * w0);
    float d1yp = RH * (C1A * (py[0] - py[4]) + C1B * (py[3] - py[1]));
    float d1xp = RH * (C1A * (px[0] - px[4]) + C1B * (px[3] - px[1]));
    float ty = d2yw + d1yp;
    float tx = d2xw + d1xp;
    float zy = ayg[y] * zety[id] + byg[y] * ty;
    float zx = axg[x] * zetx[id] + bxg[x] * tx;
    zety[id] = zy;
    zetx[id] = zx;
    return ty + zy + tx + zx;
}

// One launch per timestep: full CPML + time update for both fields.
// Also records receivers for step t-1 (wfcsc at entry == wfnsc of previous
// step, complete by launch ordering).
__global__ void step_kernel(int t,
    const float* __restrict__ wfc,   float* __restrict__ wfp,
    const float* __restrict__ wfcsc, float* __restrict__ wfpsc,
    const float* __restrict__ psiyO,   const float* __restrict__ psixO,
    float* __restrict__ psiyN,         float* __restrict__ psixN,
    const float* __restrict__ psiyscO, const float* __restrict__ psixscO,
    float* __restrict__ psiyscN,       float* __restrict__ psixscN,
    float* __restrict__ zety,   float* __restrict__ zetx,
    float* __restrict__ zetysc, float* __restrict__ zetxsc,
    const float* __restrict__ v2dt2, const float* __restrict__ spv,
    const float* __restrict__ ay, const float* __restrict__ by,
    const float* __restrict__ ax, const float* __restrict__ bx,
    const float* __restrict__ amps, const int* __restrict__ sloc,
    const int* __restrict__ rloc, float* __restrict__ out)
{
    int idx = blockIdx.x * blockDim.x + threadIdx.x;

    if (idx < NSH * NRECV && t > 0) {
        int b = idx / NRECV;
        int ry = rloc[idx * 2 + 0] + PADW;
        int rx = rloc[idx * 2 + 1] + PADW;
        out[idx * NTT + (t - 1)] = wfcsc[b * NP + ry * NXP + rx];
    }

    if (idx >= TOTC) return;
    int b = (idx >= NP) ? 1 : 0;
    int cell = idx - b * NP;
    int y = cell / NXP;
    int x = cell - y * NXP;
    int base = b * NP;

    float lap = fused_lap(wfc, psiyO, psixO, psiyN, psixN,
                          zety, zetx, base, idx, y, x, ay, by, ax, bx);
    float lapsc = fused_lap(wfcsc, psiyscO, psixscO, psiyscN, psixscN,
                            zetysc, zetxsc, base, idx, y, x, ay, by, ax, bx);

    float v2 = v2dt2[cell];
    float wn   = v2 * lap   + 2.0f * wfc[idx]   - wfp[idx];
    float wnsc = v2 * lapsc + 2.0f * wfcsc[idx] - wfpsc[idx] + spv[cell] * lap;

    int sy0 = sloc[0] + PADW, sx0 = sloc[1] + PADW;
    int sy1 = sloc[2] + PADW, sx1 = sloc[3] + PADW;
    if (b == 0 && y == sy0 && x == sx0) wn += v2 * amps[t];
    if (b == 1 && y == sy1 && x == sx1) wn += v2 * amps[NTT + t];

    wfp[idx]   = wn;
    wfpsc[idx] = wnsc;
}

__global__ void record_kernel(const float* __restrict__ wfcsc,
                              const int* __restrict__ rloc,
                              float* __restrict__ out) {
    int idx = threadIdx.x;
    if (idx < NSH * NRECV) {
        int b = idx / NRECV;
        int ry = rloc[idx * 2 + 0] + PADW;
        int rx = rloc[idx * 2 + 1] + PADW;
        out[idx * NTT + (NTT - 1)] = wfcsc[b * NP + ry * NXP + rx];
    }
}

extern "C" void kernel_launch(void* const* d_in, const int* in_sizes, int n_in,
                              void* d_out, int out_size, void* d_ws, size_t ws_size,
                              hipStream_t stream) {
    const float* v    = (const float*)d_in[0];
    const float* scat = (const float*)d_in[1];
    const float* amps = (const float*)d_in[2];
    const int* sloc = (const int*)d_in[3];
    const int* rloc = (const int*)d_in[4];
    float* ws = (float*)d_ws;
    float* out = (float*)d_out;

    float* ay  = ws + OFF_AY;
    float* by  = ws + OFF_BY;
    float* ax  = ws + OFF_AX;
    float* bx  = ws + OFF_BX;
    float* v2  = ws + OFF_V2;
    float* spv = ws + OFF_SPV;
    float* F   = ws + OFF_F;

    float* wfc     = F + 0  * TOTC;
    float* wfp     = F + 1  * TOTC;
    float* zety    = F + 2  * TOTC;
    float* zetx    = F + 3  * TOTC;
    float* wfcsc   = F + 4  * TOTC;
    float* wfpsc   = F + 5  * TOTC;
    float* zetysc  = F + 6  * TOTC;
    float* zetxsc  = F + 7  * TOTC;
    float* psiyA   = F + 8  * TOTC;
    float* psixA   = F + 9  * TOTC;
    float* psiyscA = F + 10 * TOTC;
    float* psixscA = F + 11 * TOTC;
    float* psiyB   = F + 12 * TOTC;
    float* psixB   = F + 13 * TOTC;
    float* psiyscB = F + 14 * TOTC;
    float* psixscB = F + 15 * TOTC;

    // zero the 16 field arrays (ws is poisoned 0xAA before every timed call)
    hipMemsetAsync(F, 0, sizeof(float) * 16 * TOTC, stream);

    reduce_max_kernel<<<1, 256, 0, stream>>>(v, ws + OFF_MAXV);
    setup_kernel<<<(NP + 255) / 256, 256, 0, stream>>>(
        v, scat, ws + OFF_MAXV, ay, by, ax, bx, v2, spv);

    for (int t = 0; t < NTT; ++t) {
        step_kernel<<<CELL_BLOCKS, 256, 0, stream>>>(
            t, wfc, wfp, wfcsc, wfpsc,
            psiyA, psixA, psiyB, psixB,
            psiyscA, psixscA, psiyscB, psixscB,
            zety, zetx, zetysc, zetxsc,
            v2, spv, ay, by, ax, bx, amps, sloc, rloc, out);
        float* tmp;
        tmp = wfc;   wfc = wfp;     wfp = tmp;
        tmp = wfcsc; wfcsc = wfpsc; wfpsc = tmp;
        tmp = psiyA;   psiyA = psiyB;     psiyB = tmp;
        tmp = psixA;   psixA = psixB;     psixB = tmp;
        tmp = psiyscA; psiyscA = psiyscB; psiyscB = tmp;
        tmp = psixscA; psixscA = psixscB; psixscB = tmp;
    }
    record_kernel<<<1, 256, 0, stream>>>(wfcsc, rloc, out);
}

// Round 3
// 1020.325 us; speedup vs baseline: 3.8319x; 1.4102x over previous
//
#include <hip/hip_runtime.h>

// ---- problem constants (match reference) ----
#define NYI 200
#define NXI 200
#define PMLW 20
#define FDP 2
#define PADW (PMLW + FDP)          // 22
#define NYP (NYI + 2 * PADW)       // 244
#define NXP (NXI + 2 * PADW)       // 244
#define NP  (NYP * NXP)            // 59536
#define NSH 2
#define NRECV 100
#define NTT 120
#define TOTC (NSH * NP)            // 119072

#define DTC   0.0005f
#define RH    0.25f                // 1/DY = 1/DX
#define RH2   0.0625f              // 1/DY^2
#define C1A   (1.0f / 12.0f)
#define C1B   (2.0f / 3.0f)
#define C2A   (1.0f / 12.0f)
#define C2B   (4.0f / 3.0f)

// ---- time-tiling config ----
#define KST   4                    // timesteps per launch
#define HALO  (4 * KST)            // 16 (dependency radius 4/step)
#define OUTY  32
#define OUTX  16
#define SY    (OUTY + 2 * HALO)    // 64
#define SX    (OUTX + 2 * HALO)    // 48
#define SCELL (SY * SX)            // 3072
#define TBT   512
#define CPT   (SCELL / TBT)        // 6 cells per thread
#define TILESY ((NYP + OUTY - 1) / OUTY)   // 8
#define TILESX ((NXP + OUTX - 1) / OUTX)   // 16
#define NBLK  (TILESY * TILESX * NSH)      // 256

// ---- workspace layout (float offsets) ----
#define OFF_MAXV 0
#define OFF_AY   64
#define OFF_BY   (OFF_AY + NYP)
#define OFF_AX   (OFF_BY + NYP)
#define OFF_BX   (OFF_AX + NXP)
#define OFF_V2   (OFF_BX + NXP)
#define OFF_SPV  (OFF_V2 + NP)
#define OFF_F    (OFF_SPV + NP)    // 2 banks x 12 arrays x TOTC floats

__global__ void reduce_max_kernel(const float* __restrict__ v, float* __restrict__ out) {
    __shared__ float sm[256];
    float m = 0.0f;
    for (int i = threadIdx.x; i < NYI * NXI; i += 256)
        m = fmaxf(m, v[i]);
    sm[threadIdx.x] = m;
    __syncthreads();
    for (int s = 128; s > 0; s >>= 1) {
        if (threadIdx.x < s) sm[threadIdx.x] = fmaxf(sm[threadIdx.x], sm[threadIdx.x + s]);
        __syncthreads();
    }
    if (threadIdx.x == 0) out[0] = sm[0];
}

__global__ void setup_kernel(const float* __restrict__ v,
                             const float* __restrict__ scat,
                             const float* __restrict__ maxv,
                             float* __restrict__ ay, float* __restrict__ by,
                             float* __restrict__ ax, float* __restrict__ bx,
                             float* __restrict__ v2dt2, float* __restrict__ spv) {
    int gtid = blockIdx.x * blockDim.x + threadIdx.x;
    int nth  = gridDim.x * blockDim.x;

    for (int idx = gtid; idx < NP; idx += nth) {
        int y = idx / NXP;
        int x = idx - y * NXP;
        int yi = min(max(y - PADW, 0), NYI - 1);
        int xi = min(max(x - PADW, 0), NXI - 1);
        float vp = v[yi * NXI + xi];
        v2dt2[idx] = vp * vp * DTC * DTC;
        float sp = 0.0f;
        int ys = y - PADW, xs = x - PADW;
        if (ys >= 0 && ys < NYI && xs >= 0 && xs < NXI)
            sp = scat[ys * NXI + xs];
        spv[idx] = 2.0f * vp * DTC * DTC * sp;
    }

    if (gtid < NYP + NXP) {
        float mv = maxv[0];
        int isY = gtid < NYP;
        int j   = isY ? gtid : gtid - NYP;
        int n   = isY ? NYP : NXP;
        float h = 4.0f;
        float xf = (float)j;
        float lo = (float)(FDP + PMLW);
        float hi = (float)(n - 1 - FDP - PMLW);
        float d1 = fminf(fmaxf((lo - xf) / (float)PMLW, 0.0f), 1.0f);
        float d2 = fminf(fmaxf((xf - hi) / (float)PMLW, 0.0f), 1.0f);
        float d  = fmaxf(d1, d2);
        float sigma = 3.0f * mv * 6.9077552790f / (2.0f * (float)PMLW * h) * d * d;
        float alpha = 6.2831853072f * 25.0f * (1.0f - d);
        float a  = expf(-(sigma + alpha) * DTC);
        float bb = sigma / (sigma + alpha + 1e-9f) * (a - 1.0f);
        if (isY) { ay[j] = a; by[j] = bb; }
        else     { ax[j] = a; bx[j] = bb; }
    }
}

// Time-tiled kernel: each block owns a 32x16 output tile of one shot, stages
// a 64x48 region (halo = 16 = 4*KST) of {w, psiy, psix} x {bg,sc} into LDS,
// keeps pointwise state (zeta, w_prev, constants) in registers, and runs
// KST=4 full timesteps internally. The valid region shrinks by 4 per step
// (psi phase -2, w phase -2); halo cells are recomputed with bit-identical
// arithmetic, so tiles agree on shared cells. Only the interior tile is
// written back (to the other global bank -> no inter-block races).
// Global bank layout (12 arrays x TOTC):
//  0 wfc, 1 wfp, 2 psiy, 3 psix, 4 zety, 5 zetx,
//  6 wfcsc, 7 wfpsc, 8 psiysc, 9 psixsc, 10 zetysc, 11 zetxsc
__global__ __launch_bounds__(TBT)
void tstep_kernel(int t0,
    const float* __restrict__ Gin, float* __restrict__ Gout,
    const float* __restrict__ v2g, const float* __restrict__ spg,
    const float* __restrict__ ayg, const float* __restrict__ byg,
    const float* __restrict__ axg, const float* __restrict__ bxg,
    const float* __restrict__ amps, const int* __restrict__ sloc,
    const int* __restrict__ rloc, float* __restrict__ out)
{
    __shared__ float sW[2][2][SCELL];   // [time-buf][field]
    __shared__ float sPy[2][SCELL];     // [field]
    __shared__ float sPx[2][SCELL];

    const int tid  = threadIdx.x;
    const int bid  = blockIdx.x;
    const int shot = bid / (TILESY * TILESX);
    const int rem  = bid % (TILESY * TILESX);
    const int tyid = rem / TILESX;
    const int txid = rem % TILESX;
    const int oy = tyid * OUTY - HALO;
    const int ox = txid * OUTX - HALO;
    const int fb = shot * NP;

    // ---- stage neighbor-accessed arrays into LDS (OOB -> 0) ----
    for (int i = tid; i < SCELL; i += TBT) {
        int ly = i / SX, lx = i - ly * SX;
        int gy = oy + ly, gx = ox + lx;
        bool ib = (unsigned)gy < (unsigned)NYP && (unsigned)gx < (unsigned)NXP;
        int g = fb + gy * NXP + gx;
        sW[0][0][i] = ib ? Gin[0 * TOTC + g] : 0.f;
        sW[0][1][i] = ib ? Gin[6 * TOTC + g] : 0.f;
        sPy[0][i]   = ib ? Gin[2 * TOTC + g] : 0.f;
        sPx[0][i]   = ib ? Gin[3 * TOTC + g] : 0.f;
        sPy[1][i]   = ib ? Gin[8 * TOTC + g] : 0.f;
        sPx[1][i]   = ib ? Gin[9 * TOTC + g] : 0.f;
    }

    // ---- per-owned-cell register state ----
    int   gidr[CPT], dmn[CPT];
    bool  outfr[CPT];
    float ayc[CPT], byc[CPT], axc[CPT], bxc[CPT], v2c[CPT], spc[CPT], srcv[CPT];
    float zyB[CPT], zxB[CPT], zyS[CPT], zxS[CPT], wpB[CPT], wpS[CPT];

    const int sy = sloc[shot * 2 + 0] + PADW;
    const int sx = sloc[shot * 2 + 1] + PADW;

#pragma unroll
    for (int j = 0; j < CPT; ++j) {
        int li = tid + j * TBT;
        int ly = li / SX, lx = li - ly * SX;
        int gy = oy + ly, gx = ox + lx;
        bool ib = (unsigned)gy < (unsigned)NYP && (unsigned)gx < (unsigned)NXP;
        int cg = gy * NXP + gx;
        int g  = fb + cg;
        gidr[j]  = g;
        dmn[j]   = min(min(ly, lx), min(SY - 1 - ly, SX - 1 - lx));
        outfr[j] = ib && (unsigned)(ly - HALO) < (unsigned)OUTY
                      && (unsigned)(lx - HALO) < (unsigned)OUTX;
        ayc[j] = ib ? ayg[gy] : 0.f;  byc[j] = ib ? byg[gy] : 0.f;
        axc[j] = ib ? axg[gx] : 0.f;  bxc[j] = ib ? bxg[gx] : 0.f;
        v2c[j] = ib ? v2g[cg] : 0.f;  spc[j] = ib ? spg[cg] : 0.f;
        srcv[j] = (ib && gy == sy && gx == sx) ? v2c[j] : 0.f;
        zyB[j] = ib ? Gin[4  * TOTC + g] : 0.f;
        zxB[j] = ib ? Gin[5  * TOTC + g] : 0.f;
        zyS[j] = ib ? Gin[10 * TOTC + g] : 0.f;
        zxS[j] = ib ? Gin[11 * TOTC + g] : 0.f;
        wpB[j] = ib ? Gin[1  * TOTC + g] : 0.f;
        wpS[j] = ib ? Gin[7  * TOTC + g] : 0.f;
    }
    __syncthreads();

    int cur = 0;
#pragma unroll
    for (int s = 0; s < KST; ++s) {
        const int t  = t0 + s;
        const int mA = 4 * s + 2;
        const int mB = 4 * s + 4;
        const float* wB = sW[cur][0];
        const float* wS = sW[cur][1];

        // ---- phase A: psi update (needs w radius 2; valid margin 4s) ----
#pragma unroll
        for (int j = 0; j < CPT; ++j) {
            if (dmn[j] < mA) continue;
            int li = tid + j * TBT;
            float d1y = RH * (C1A * (wB[li - 2 * SX] - wB[li + 2 * SX]) +
                              C1B * (wB[li + SX]     - wB[li - SX]));
            float d1x = RH * (C1A * (wB[li - 2] - wB[li + 2]) +
                              C1B * (wB[li + 1] - wB[li - 1]));
            sPy[0][li] = ayc[j] * sPy[0][li] + byc[j] * d1y;
            sPx[0][li] = axc[j] * sPx[0][li] + bxc[j] * d1x;

            float d1ys = RH * (C1A * (wS[li - 2 * SX] - wS[li + 2 * SX]) +
                               C1B * (wS[li + SX]     - wS[li - SX]));
            float d1xs = RH * (C1A * (wS[li - 2] - wS[li + 2]) +
                               C1B * (wS[li + 1] - wS[li - 1]));
            sPy[1][li] = ayc[j] * sPy[1][li] + byc[j] * d1ys;
            sPx[1][li] = axc[j] * sPx[1][li] + bxc[j] * d1xs;
        }
        __syncthreads();

        // ---- phase B: zeta + time update ----
        float* wnB = sW[cur ^ 1][0];
        float* wnS = sW[cur ^ 1][1];
        const float ampv = amps[shot * NTT + t];
#pragma unroll
        for (int j = 0; j < CPT; ++j) {
            if (dmn[j] < mB) continue;
            int li = tid + j * TBT;

            float w0 = wB[li];
            float d2y = RH2 * (C2B * (wB[li - SX] + wB[li + SX]) -
                               C2A * (wB[li - 2 * SX] + wB[li + 2 * SX]) - 2.5f * w0);
            float d2x = RH2 * (C2B * (wB[li - 1] + wB[li + 1]) -
                               C2A * (wB[li - 2] + wB[li + 2]) - 2.5f * w0);
            float d1yp = RH * (C1A * (sPy[0][li - 2 * SX] - sPy[0][li + 2 * SX]) +
                               C1B * (sPy[0][li + SX]     - sPy[0][li - SX]));
            float d1xp = RH * (C1A * (sPx[0][li - 2] - sPx[0][li + 2]) +
                               C1B * (sPx[0][li + 1] - sPx[0][li - 1]));
            float ty = d2y + d1yp;
            float tx = d2x + d1xp;
            zyB[j] = ayc[j] * zyB[j] + byc[j] * ty;
            zxB[j] = axc[j] * zxB[j] + bxc[j] * tx;
            float lap = ty + zyB[j] + tx + zxB[j];

            float ws0 = wS[li];
            float d2ys = RH2 * (C2B * (wS[li - SX] + wS[li + SX]) -
                                C2A * (wS[li - 2 * SX] + wS[li + 2 * SX]) - 2.5f * ws0);
            float d2xs = RH2 * (C2B * (wS[li - 1] + wS[li + 1]) -
                                C2A * (wS[li - 2] + wS[li + 2]) - 2.5f * ws0);
            float d1yps = RH * (C1A * (sPy[1][li - 2 * SX] - sPy[1][li + 2 * SX]) +
                                C1B * (sPy[1][li + SX]     - sPy[1][li - SX]));
            float d1xps = RH * (C1A * (sPx[1][li - 2] - sPx[1][li + 2]) +
                                C1B * (sPx[1][li + 1] - sPx[1][li - 1]));
            float tys = d2ys + d1yps;
            float txs = d2xs + d1xps;
            zyS[j] = ayc[j] * zyS[j] + byc[j] * tys;
            zxS[j] = axc[j] * zxS[j] + bxc[j] * txs;
            float lapsc = tys + zyS[j] + txs + zxS[j];

            float wn   = v2c[j] * lap   + 2.0f * w0  - wpB[j] + srcv[j] * ampv;
            float wnsc = v2c[j] * lapsc + 2.0f * ws0 - wpS[j] + spc[j] * lap;
            wnB[li] = wn;
            wnS[li] = wnsc;
            wpB[j] = w0;
            wpS[j] = ws0;
        }
        __syncthreads();
        cur ^= 1;

        // ---- record receivers for step t (scattered field, post-update) ----
        if (tid < NSH * NRECV) {
            int rb = tid / NRECV;
            if (rb == shot) {
                int ry = rloc[tid * 2 + 0] + PADW;
                int rx = rloc[tid * 2 + 1] + PADW;
                if (ry / OUTY == tyid && rx / OUTX == txid)
                    out[tid * NTT + t] = sW[cur][1][(ry - oy) * SX + (rx - ox)];
            }
        }
    }

    // ---- write back interior tile (all 12 state arrays) ----
#pragma unroll
    for (int j = 0; j < CPT; ++j) {
        if (!outfr[j]) continue;
        int li = tid + j * TBT;
        int g  = gidr[j];
        Gout[0  * TOTC + g] = sW[cur][0][li];
        Gout[1  * TOTC + g] = wpB[j];
        Gout[2  * TOTC + g] = sPy[0][li];
        Gout[3  * TOTC + g] = sPx[0][li];
        Gout[4  * TOTC + g] = zyB[j];
        Gout[5  * TOTC + g] = zxB[j];
        Gout[6  * TOTC + g] = sW[cur][1][li];
        Gout[7  * TOTC + g] = wpS[j];
        Gout[8  * TOTC + g] = sPy[1][li];
        Gout[9  * TOTC + g] = sPx[1][li];
        Gout[10 * TOTC + g] = zyS[j];
        Gout[11 * TOTC + g] = zxS[j];
    }
}

extern "C" void kernel_launch(void* const* d_in, const int* in_sizes, int n_in,
                              void* d_out, int out_size, void* d_ws, size_t ws_size,
                              hipStream_t stream) {
    const float* v    = (const float*)d_in[0];
    const float* scat = (const float*)d_in[1];
    const float* amps = (const float*)d_in[2];
    const int* sloc = (const int*)d_in[3];
    const int* rloc = (const int*)d_in[4];
    float* ws = (float*)d_ws;
    float* out = (float*)d_out;

    float* ay  = ws + OFF_AY;
    float* by  = ws + OFF_BY;
    float* ax  = ws + OFF_AX;
    float* bx  = ws + OFF_BX;
    float* v2  = ws + OFF_V2;
    float* spv = ws + OFF_SPV;
    float* bank0 = ws + OFF_F;
    float* bank1 = bank0 + 12 * TOTC;

    // zero initial state bank (ws is poisoned 0xAA before every timed call).
    // bank1 needs no zeroing: every launch fully overwrites every in-domain
    // cell of all 12 arrays in its output bank.
    hipMemsetAsync(bank0, 0, sizeof(float) * 12 * TOTC, stream);

    reduce_max_kernel<<<1, 256, 0, stream>>>(v, ws + OFF_MAXV);
    setup_kernel<<<(NP + 255) / 256, 256, 0, stream>>>(
        v, scat, ws + OFF_MAXV, ay, by, ax, bx, v2, spv);

    float* gin  = bank0;
    float* gout = bank1;
    for (int t0 = 0; t0 < NTT; t0 += KST) {
        tstep_kernel<<<NBLK, TBT, 0, stream>>>(
            t0, gin, gout, v2, spv, ay, by, ax, bx, amps, sloc, rloc, out);
        float* tmp = gin; gin = gout; gout = tmp;
    }
    // receivers are recorded in-kernel for every t; no epilogue needed.
}

// Round 4
// 551.140 us; speedup vs baseline: 7.0940x; 1.8513x over previous
//
#include <hip/hip_runtime.h>

// ---- problem constants (match reference) ----
#define NYI 200
#define NXI 200
#define PMLW 20
#define FDP 2
#define PADW (PMLW + FDP)          // 22
#define NYP (NYI + 2 * PADW)       // 244
#define NXP (NXI + 2 * PADW)       // 244
#define NP  (NYP * NXP)            // 59536
#define NSH 2
#define NRECV 100
#define NTT 120
#define TOTC (NSH * NP)            // 119072

#define DTC   0.0005f
#define RH    0.25f                // 1/DY = 1/DX
#define RH2   0.0625f              // 1/DY^2
#define C1A   (1.0f / 12.0f)
#define C1B   (2.0f / 3.0f)
#define C2A   (1.0f / 12.0f)
#define C2B   (4.0f / 3.0f)

// ---- time-tiling config (quad = 4 contiguous x-cells per thread) ----
#define KST   4                    // timesteps per launch
#define HALO  (4 * KST)            // 16
#define OUTY  32
#define OUTX  16
#define SY    (OUTY + 2 * HALO)    // 64
#define SX    (OUTX + 2 * HALO)    // 48
#define QX    (SX / 4)             // 12 quads per row
#define NQ    (SY * QX)            // 768 quads
#define TBT   NQ                   // 768 threads, 1 quad/thread
#define TILESY ((NYP + OUTY - 1) / OUTY)   // 8
#define TILESX ((NXP + OUTX - 1) / OUTX)   // 16
#define NBLK  (TILESY * TILESX * NSH)      // 256

typedef float f4 __attribute__((ext_vector_type(4)));

// ---- workspace layout (float offsets) ----
#define OFF_MAXV 0
#define OFF_AY   64
#define OFF_BY   (OFF_AY + NYP)
#define OFF_AX   (OFF_BY + NYP)
#define OFF_BX   (OFF_AX + NXP)
#define OFF_V2   (OFF_BX + NXP)
#define OFF_SPV  (OFF_V2 + NP)
#define OFF_F    (OFF_SPV + NP)    // 2 banks x 12 arrays x TOTC floats

__global__ void reduce_max_kernel(const float* __restrict__ v, float* __restrict__ out) {
    __shared__ float sm[256];
    float m = 0.0f;
    for (int i = threadIdx.x; i < NYI * NXI; i += 256)
        m = fmaxf(m, v[i]);
    sm[threadIdx.x] = m;
    __syncthreads();
    for (int s = 128; s > 0; s >>= 1) {
        if (threadIdx.x < s) sm[threadIdx.x] = fmaxf(sm[threadIdx.x], sm[threadIdx.x + s]);
        __syncthreads();
    }
    if (threadIdx.x == 0) out[0] = sm[0];
}

__global__ void setup_kernel(const float* __restrict__ v,
                             const float* __restrict__ scat,
                             const float* __restrict__ maxv,
                             float* __restrict__ ay, float* __restrict__ by,
                             float* __restrict__ ax, float* __restrict__ bx,
                             float* __restrict__ v2dt2, float* __restrict__ spv) {
    int gtid = blockIdx.x * blockDim.x + threadIdx.x;
    int nth  = gridDim.x * blockDim.x;

    for (int idx = gtid; idx < NP; idx += nth) {
        int y = idx / NXP;
        int x = idx - y * NXP;
        int yi = min(max(y - PADW, 0), NYI - 1);
        int xi = min(max(x - PADW, 0), NXI - 1);
        float vp = v[yi * NXI + xi];
        v2dt2[idx] = vp * vp * DTC * DTC;
        float sp = 0.0f;
        int ys = y - PADW, xs = x - PADW;
        if (ys >= 0 && ys < NYI && xs >= 0 && xs < NXI)
            sp = scat[ys * NXI + xs];
        spv[idx] = 2.0f * vp * DTC * DTC * sp;
    }

    if (gtid < NYP + NXP) {
        float mv = maxv[0];
        int isY = gtid < NYP;
        int j   = isY ? gtid : gtid - NYP;
        int n   = isY ? NYP : NXP;
        float h = 4.0f;
        float xf = (float)j;
        float lo = (float)(FDP + PMLW);
        float hi = (float)(n - 1 - FDP - PMLW);
        float d1 = fminf(fmaxf((lo - xf) / (float)PMLW, 0.0f), 1.0f);
        float d2 = fminf(fmaxf((xf - hi) / (float)PMLW, 0.0f), 1.0f);
        float d  = fmaxf(d1, d2);
        float sigma = 3.0f * mv * 6.9077552790f / (2.0f * (float)PMLW * h) * d * d;
        float alpha = 6.2831853072f * 25.0f * (1.0f - d);
        float a  = expf(-(sigma + alpha) * DTC);
        float bb = sigma / (sigma + alpha + 1e-9f) * (a - 1.0f);
        if (isY) { ay[j] = a; by[j] = bb; }
        else     { ax[j] = a; bx[j] = bb; }
    }
}

// Assemble x-shifted float4 vectors for cells [4q..4q+3] from aligned quads
// L (cells-4..-1), C (0..3), R (+4..+7). Pure register selects.
__device__ __forceinline__ void xshift(const f4 L, const f4 C, const f4 R,
                                       f4& m2, f4& m1, f4& p1, f4& p2) {
    m2 = (f4){L.z, L.w, C.x, C.y};
    m1 = (f4){L.w, C.x, C.y, C.z};
    p1 = (f4){C.y, C.z, C.w, R.x};
    p2 = (f4){C.z, C.w, R.x, R.y};
}

// Time-tiled kernel, float4 granularity. One thread owns one aligned 4-cell
// quad of a 64x48 staged region (32x16 output tile, halo 16 = 4*KST).
// All LDS stencil traffic is b128; w-quads read in phase A are stashed in
// registers across the barrier for phase B. Quad-level masking by margin:
// any stencil input with margin >= m lies in a computed quad (margin lemma),
// garbage is confined to cells never consumed by valid outputs.
__global__ __launch_bounds__(TBT)
void tstep_kernel(int t0,
    const float* __restrict__ Gin, float* __restrict__ Gout,
    const float* __restrict__ v2g, const float* __restrict__ spg,
    const float* __restrict__ ayg, const float* __restrict__ byg,
    const float* __restrict__ axg, const float* __restrict__ bxg,
    const float* __restrict__ amps, const int* __restrict__ sloc,
    const int* __restrict__ rloc, float* __restrict__ out)
{
    __shared__ f4 sW[2][2][NQ];   // [time-buf][field][quad]
    __shared__ f4 sPy[2][NQ];     // [field]
    __shared__ f4 sPx[2][NQ];

    const int tid  = threadIdx.x;
    const int bid  = blockIdx.x;
    const int shot = bid / (TILESY * TILESX);
    const int rem  = bid % (TILESY * TILESX);
    const int tyid = rem / TILESX;
    const int txid = rem % TILESX;
    const int oy = tyid * OUTY - HALO;
    const int ox = txid * OUTX - HALO;
    const int fb = shot * NP;

    const int ly  = tid / QX;
    const int qx  = tid - ly * QX;
    const int lx0 = 4 * qx;
    const int gy  = oy + ly;
    const int gx0 = ox + lx0;
    const bool iby = (unsigned)gy  < (unsigned)NYP;
    const bool ibx = (unsigned)gx0 < (unsigned)NXP;  // quads never straddle (NXP%4==0)
    const bool ib  = iby && ibx;
    const int g = ib ? (fb + gy * NXP + gx0) : 0;    // 16B-aligned

    const f4 z4 = {0.f, 0.f, 0.f, 0.f};
    #define LD4(p) (*reinterpret_cast<const f4*>(p))

    // ---- stage (all b128, coalesced) ----
    sW[0][0][tid] = ib ? LD4(Gin + 0 * TOTC + g) : z4;
    sW[0][1][tid] = ib ? LD4(Gin + 6 * TOTC + g) : z4;
    sW[1][0][tid] = z4;
    sW[1][1][tid] = z4;
    sPy[0][tid]   = ib ? LD4(Gin + 2 * TOTC + g) : z4;
    sPx[0][tid]   = ib ? LD4(Gin + 3 * TOTC + g) : z4;
    sPy[1][tid]   = ib ? LD4(Gin + 8 * TOTC + g) : z4;
    sPx[1][tid]   = ib ? LD4(Gin + 9 * TOTC + g) : z4;

    f4 wpv[2], zyv[2], zxv[2];
    wpv[0] = ib ? LD4(Gin + 1  * TOTC + g) : z4;
    wpv[1] = ib ? LD4(Gin + 7  * TOTC + g) : z4;
    zyv[0] = ib ? LD4(Gin + 4  * TOTC + g) : z4;
    zyv[1] = ib ? LD4(Gin + 10 * TOTC + g) : z4;
    zxv[0] = ib ? LD4(Gin + 5  * TOTC + g) : z4;
    zxv[1] = ib ? LD4(Gin + 11 * TOTC + g) : z4;

    // ---- per-quad constants (zeroed OOB -> state stays exactly 0 there) ----
    const float ayv = ib ? ayg[gy] : 0.f;
    const float byv = ib ? byg[gy] : 0.f;
    f4 axv = z4, bxv = z4, v2v = z4, spvv = z4;
    if (ib) {
        axv  = LD4(axg + gx0);
        bxv  = LD4(bxg + gx0);
        v2v  = LD4(v2g + gy * NXP + gx0);
        spvv = LD4(spg + gy * NXP + gx0);
    }
    f4 srcv = z4;
    {
        const int sy = sloc[shot * 2 + 0] + PADW;
        const int sx = sloc[shot * 2 + 1] + PADW;
        #pragma unroll
        for (int c = 0; c < 4; ++c)
            if (ib && gy == sy && gx0 + c == sx) srcv[c] = v2v[c];
    }

    // quad margin: min(y-margin, best cell x-margin)
    const int my = min(ly, SY - 1 - ly);
    int mxmax = 0;
    #pragma unroll
    for (int c = 0; c < 4; ++c)
        mxmax = max(mxmax, min(lx0 + c, SX - 1 - (lx0 + c)));
    const int mq = min(my, mxmax);

    const int qiL = tid - (qx > 0 ? 1 : 0);
    const int qiR = tid + (qx < QX - 1 ? 1 : 0);

    float ampv[KST];
    #pragma unroll
    for (int s = 0; s < KST; ++s) ampv[s] = amps[shot * NTT + t0 + s];

    bool recOwn = false; int rq = 0, rc = 0, rout = 0;
    if (tid < NSH * NRECV) {
        int rb = tid / NRECV;
        int ry = rloc[tid * 2 + 0] + PADW;
        int rx = rloc[tid * 2 + 1] + PADW;
        if (rb == shot && ry / OUTY == tyid && rx / OUTX == txid) {
            recOwn = true;
            int lry = ry - oy, lrx = rx - ox;
            rq = lry * QX + (lrx >> 2);
            rc = lrx & 3;
            rout = tid * NTT;
        }
    }
    __syncthreads();

    int cur = 0;
    #pragma unroll
    for (int s = 0; s < KST; ++s) {
        const int mA = 4 * s + 2;
        const int mB = 4 * s + 4;
        f4 wst[2][7];   // stashed w quads: m2,m1,C,p1,p2,L,R per field
        f4 pxC[2];      // own psix post-update (phase B needs it)

        // ---- phase A: psi rmw (reads w; all b128) ----
        if (mq >= mA) {
            #pragma unroll
            for (int f = 0; f < 2; ++f) {
                const f4* w = sW[cur][f];
                f4 m2 = w[tid - 2 * QX], m1 = w[tid - QX], C = w[tid];
                f4 p1 = w[tid + QX],     p2 = w[tid + 2 * QX];
                f4 L = w[qiL], R = w[qiR];
                wst[f][0] = m2; wst[f][1] = m1; wst[f][2] = C;
                wst[f][3] = p1; wst[f][4] = p2; wst[f][5] = L; wst[f][6] = R;
                f4 xm2, xm1, xp1, xp2;
                xshift(L, C, R, xm2, xm1, xp1, xp2);
                f4 d1y = RH * (C1A * (m2 - p2) + C1B * (p1 - m1));
                f4 d1x = RH * (C1A * (xm2 - xp2) + C1B * (xp1 - xm1));
                f4 py = ayv * sPy[f][tid] + byv * d1y;
                f4 px = axv * sPx[f][tid] + bxv * d1x;
                sPy[f][tid] = py;
                sPx[f][tid] = px;
                pxC[f] = px;
            }
        }
        __syncthreads();

        // ---- phase B: zeta + time update (w from stash) ----
        if (mq >= mB) {
            f4 lap0 = z4;
            #pragma unroll
            for (int f = 0; f < 2; ++f) {
                f4 m2 = wst[f][0], m1 = wst[f][1], C = wst[f][2];
                f4 p1 = wst[f][3], p2 = wst[f][4], L = wst[f][5], R = wst[f][6];
                f4 xm2, xm1, xp1, xp2;
                xshift(L, C, R, xm2, xm1, xp1, xp2);
                f4 d2y = RH2 * (C2B * (m1 + p1) - C2A * (m2 + p2) - 2.5f * C);
                f4 d2x = RH2 * (C2B * (xm1 + xp1) - C2A * (xm2 + xp2) - 2.5f * C);

                f4 pym2 = sPy[f][tid - 2 * QX], pym1 = sPy[f][tid - QX];
                f4 pyp1 = sPy[f][tid + QX],     pyp2 = sPy[f][tid + 2 * QX];
                f4 d1yp = RH * (C1A * (pym2 - pyp2) + C1B * (pyp1 - pym1));

                f4 pL = sPx[f][qiL], pR = sPx[f][qiR], pC = pxC[f];
                f4 pxm2, pxm1, pxp1, pxp2;
                xshift(pL, pC, pR, pxm2, pxm1, pxp1, pxp2);
                f4 d1xp = RH * (C1A * (pxm2 - pxp2) + C1B * (pxp1 - pxm1));

                f4 ty = d2y + d1yp;
                f4 tx = d2x + d1xp;
                zyv[f] = ayv * zyv[f] + byv * ty;
                zxv[f] = axv * zxv[f] + bxv * tx;
                f4 lap = ty + zyv[f] + tx + zxv[f];

                f4 wn;
                if (f == 0) {
                    lap0 = lap;
                    wn = v2v * lap + 2.0f * C - wpv[0] + srcv * ampv[s];
                } else {
                    wn = v2v * lap + 2.0f * C - wpv[1] + spvv * lap0;
                }
                wpv[f] = C;
                sW[cur ^ 1][f][tid] = wn;
            }
        }
        __syncthreads();
        cur ^= 1;

        // record receivers for step t0+s (scattered field, post-update)
        if (recOwn) out[rout + (t0 + s)] = sW[cur][1][rq][rc];
    }

    // ---- write back interior quads (all 12 arrays, b128) ----
    const bool outq = ib && (unsigned)(ly - HALO) < (unsigned)OUTY
                         && (unsigned)(lx0 - HALO) < (unsigned)OUTX;
    if (outq) {
        #define ST4(p, vv) (*reinterpret_cast<f4*>(p) = (vv))
        ST4(Gout + 0  * TOTC + g, sW[cur][0][tid]);
        ST4(Gout + 1  * TOTC + g, wpv[0]);
        ST4(Gout + 2  * TOTC + g, sPy[0][tid]);
        ST4(Gout + 3  * TOTC + g, sPx[0][tid]);
        ST4(Gout + 4  * TOTC + g, zyv[0]);
        ST4(Gout + 5  * TOTC + g, zxv[0]);
        ST4(Gout + 6  * TOTC + g, sW[cur][1][tid]);
        ST4(Gout + 7  * TOTC + g, wpv[1]);
        ST4(Gout + 8  * TOTC + g, sPy[1][tid]);
        ST4(Gout + 9  * TOTC + g, sPx[1][tid]);
        ST4(Gout + 10 * TOTC + g, zyv[1]);
        ST4(Gout + 11 * TOTC + g, zxv[1]);
    }
}

extern "C" void kernel_launch(void* const* d_in, const int* in_sizes, int n_in,
                              void* d_out, int out_size, void* d_ws, size_t ws_size,
                              hipStream_t stream) {
    const float* v    = (const float*)d_in[0];
    const float* scat = (const float*)d_in[1];
    const float* amps = (const float*)d_in[2];
    const int* sloc = (const int*)d_in[3];
    const int* rloc = (const int*)d_in[4];
    float* ws = (float*)d_ws;
    float* out = (float*)d_out;

    float* ay  = ws + OFF_AY;
    float* by  = ws + OFF_BY;
    float* ax  = ws + OFF_AX;
    float* bx  = ws + OFF_BX;
    float* v2  = ws + OFF_V2;
    float* spv = ws + OFF_SPV;
    float* bank0 = ws + OFF_F;
    float* bank1 = bank0 + 12 * TOTC;

    // zero initial state bank (ws is poisoned 0xAA before every timed call).
    // bank1 needs no zeroing: every launch fully overwrites every in-domain
    // interior quad of all 12 arrays, and OOB cells are never read (ib mask).
    hipMemsetAsync(bank0, 0, sizeof(float) * 12 * TOTC, stream);

    reduce_max_kernel<<<1, 256, 0, stream>>>(v, ws + OFF_MAXV);
    setup_kernel<<<(NP + 255) / 256, 256, 0, stream>>>(
        v, scat, ws + OFF_MAXV, ay, by, ax, bx, v2, spv);

    float* gin  = bank0;
    float* gout = bank1;
    for (int t0 = 0; t0 < NTT; t0 += KST) {
        tstep_kernel<<<NBLK, TBT, 0, stream>>>(
            t0, gin, gout, v2, spv, ay, by, ax, bx, amps, sloc, rloc, out);
        float* tmp = gin; gin = gout; gout = tmp;
    }
    // receivers are recorded in-kernel for every t; no epilogue needed.
}